// Round 1
// baseline (141.179 us; speedup 1.0000x reference)
//
#include <hip/hip_runtime.h>
#include <stdint.h>

// B=256, T=512, f32 tensors. v6: single kernel. Each wave gathers its MFMA
// B-fragments (GEMM1 K=224: conv176 + x-onehot16 + w-onehot16 + bias1 + pad;
// GEMM2 K=64: 48 + bias + pad) directly from the global float weights into
// VGPRs (no prep kernel, no d_ws). bf16 packing via v_cvt_pk_bf16_f32.
// Conv computed directly in A-fragment layout; only the GEMM1->GEMM2 H
// transpose touches LDS (2 KB/wave). No __syncthreads.
#define NTOK (256 * 512)
#define TPB 256

typedef short bf16x8 __attribute__((ext_vector_type(8)));
typedef float f32x4 __attribute__((ext_vector_type(4)));
typedef unsigned int u32x4 __attribute__((ext_vector_type(4)));
typedef unsigned short u16;
typedef unsigned int u32;

union Frag { bf16x8 h; u32x4 w; };

__device__ __forceinline__ u32 cvtpk(float lo, float hi) {
    u32 r;
    asm("v_cvt_pk_bf16_f32 %0, %1, %2" : "=v"(r) : "v"(lo), "v"(hi));
    return r;
}
__device__ __forceinline__ u16 f2bf1(float f) { return (u16)cvtpk(f, f); }

// interleaved: j = (a.x, b.x, a.y, b.y, a.z, b.z, a.w, b.w)
__device__ __forceinline__ Frag pack_il(float4 a, float4 b) {
    Frag f;
    f.w = (u32x4){cvtpk(a.x, b.x), cvtpk(a.y, b.y), cvtpk(a.z, b.z), cvtpk(a.w, b.w)};
    return f;
}
// sequential: j = (a.x, a.y, a.z, a.w, b.x, b.y, b.z, b.w)
__device__ __forceinline__ Frag pack_sq(float4 a, float4 b) {
    Frag f;
    f.w = (u32x4){cvtpk(a.x, a.y), cvtpk(a.z, a.w), cvtpk(b.x, b.y), cvtpk(b.z, b.w)};
    return f;
}

__global__ __launch_bounds__(256, 2)
void tones_v6(const int* __restrict__ widx, const int* __restrict__ xidx,
              const float* __restrict__ y,
              const float* __restrict__ Wxh, const float* __restrict__ bxh,
              const float* __restrict__ Wwh, const float* __restrict__ bwh,
              const float* __restrict__ Wyh, const float* __restrict__ byh,
              const float* __restrict__ Wconv, const float* __restrict__ bconv,
              const float* __restrict__ Whl, const float* __restrict__ bhl,
              float* __restrict__ out)
{
    __shared__ __align__(16) u16 sH[4 * 1024];   // per-wave H in A-frag layout (2 KB each)

    const int tid = threadIdx.x;
    const int wave = tid >> 6, lane = tid & 63;
    const int q = lane >> 4, c = lane & 15;

    // ---- gather B fragments directly from global weights (once per wave) ----
    // B1 element j of frag [ks][nt]: k = 32*ks + 8*q + j, n = nt*16 + c
    //   k<176 -> Wyh[n*176 + (k&1)*88 + (k>>1)] ; 176..191 -> Wxh[n*16 + k-176]
    //   192..207 -> Wwh[n*16 + k-192] ; k==208 -> bxh[n]+bwh[n]+byh[n] ; else 0
    bf16x8 B1[7][3];
    bf16x8 B2[2][6];
    #pragma unroll
    for (int nt = 0; nt < 3; nt++) {
        const int n = nt * 16 + c;
        const float* wy = Wyh + n * 176;
        #pragma unroll
        for (int ks = 0; ks < 5; ks++) {     // k = 32ks+8q+j <= 159: pure conv rows
            const float* p = wy + 16 * ks + 4 * q;       // d = 16ks+4q+(j>>1), ch = j&1
            B1[ks][nt] = pack_il(*(const float4*)p, *(const float4*)(p + 88)).h;
        }
        {   // ks=5: q<2 conv tail (d 80..87); q>=2 x-onehot dims (q-2)*8+j
            Frag f;
            if (q < 2) {
                const float* p = wy + 80 + 4 * q;
                f = pack_il(*(const float4*)p, *(const float4*)(p + 88));
            } else {
                const float* p = Wxh + n * 16 + (q - 2) * 8;
                f = pack_sq(*(const float4*)p, *(const float4*)(p + 4));
            }
            B1[5][nt] = f.h;
        }
        {   // ks=6: q<2 w-onehot dims q*8+j; q==2 bias at j=0; q==3 zeros
            Frag f;
            if (q < 2) {
                const float* p = Wwh + n * 16 + q * 8;
                f = pack_sq(*(const float4*)p, *(const float4*)(p + 4));
            } else if (q == 2) {
                f.w = (u32x4){cvtpk(bxh[n] + bwh[n] + byh[n], 0.0f), 0u, 0u, 0u};
            } else {
                f.w = (u32x4){0u, 0u, 0u, 0u};
            }
            B1[6][nt] = f.h;
        }
    }
    // B2 element j of frag [ks][nt]: k = 32ks+8q+j, dd = nt*16+c
    //   dd<88 && k<48 -> Whl[dd*48+k] ; dd<88 && k==48 -> bhl[dd] ; else 0
    #pragma unroll
    for (int nt = 0; nt < 6; nt++) {
        const int dd = nt * 16 + c;
        const bool ok = dd < 88;
        const float* wh = Whl + dd * 48;
        {   // ks=0: k = 8q+j in 0..31
            Frag f;
            if (ok) {
                const float* p = wh + 8 * q;
                f = pack_sq(*(const float4*)p, *(const float4*)(p + 4));
            } else f.w = (u32x4){0u, 0u, 0u, 0u};
            B2[0][nt] = f.h;
        }
        {   // ks=1: q<2 -> k=32+8q+j<48; q==2 -> bias at j=0; q==3 -> zeros
            Frag f; f.w = (u32x4){0u, 0u, 0u, 0u};
            if (ok) {
                if (q < 2) {
                    const float* p = wh + 32 + 8 * q;
                    f = pack_sq(*(const float4*)p, *(const float4*)(p + 4));
                } else if (q == 2) {
                    f.w[0] = cvtpk(bhl[dd], 0.0f);
                }
            }
            B2[1][nt] = f.h;
        }
    }

    const float wc00 = Wconv[0], wc01 = Wconv[1], wc02 = Wconv[2];
    const float wc10 = Wconv[3], wc11 = Wconv[4], wc12 = Wconv[5];
    const float bc0 = bconv[0], bc1 = bconv[1];

    u16* sW = sH + wave * 1024;

    #pragma unroll 1
    for (int t = 0; t < 4; t++) {
        const int tb = blockIdx.x * 256 + wave * 64 + t * 16;
        const float* yc = y + (size_t)(tb + c) * 88;     // this lane's token row
        const int xv = xidx[tb + c];
        const int wv = widx[tb + c];

        f32x4 h0 = {0, 0, 0, 0}, h1 = {0, 0, 0, 0}, h2 = {0, 0, 0, 0};

        // ---- ks=0..4: conv directly in A-frag layout (d0 = 16s + 4q) ----
        #pragma unroll
        for (int s = 0; s < 5; s++) {
            const int d0 = 16 * s + 4 * q;
            float p0 = (d0 == 0) ? 0.0f : yc[d0 - 1];
            float4 v4 = *(const float4*)(yc + d0);
            float p5 = yc[d0 + 4];                       // d0+4 <= 80 < 88
            float p[6] = {p0, v4.x, v4.y, v4.z, v4.w, p5};
            Frag af;
            #pragma unroll
            for (int i = 0; i < 4; i++) {
                float c0 = fmaf(wc00, p[i], fmaf(wc01, p[i + 1], fmaf(wc02, p[i + 2], bc0)));
                float c1 = fmaf(wc10, p[i], fmaf(wc11, p[i + 1], fmaf(wc12, p[i + 2], bc1)));
                af.w[i] = cvtpk(fmaxf(c0, 0.0f), fmaxf(c1, 0.0f));
            }
            h0 = __builtin_amdgcn_mfma_f32_16x16x32_bf16(af.h, B1[s][0], h0, 0, 0, 0);
            h1 = __builtin_amdgcn_mfma_f32_16x16x32_bf16(af.h, B1[s][1], h1, 0, 0, 0);
            h2 = __builtin_amdgcn_mfma_f32_16x16x32_bf16(af.h, B1[s][2], h2, 0, 0, 0);
        }
        // ---- ks=5: q<2 -> conv tail (d 80..87); q>=2 -> x-onehot dims (q-2)*8+j ----
        {
            Frag af;
            if (q < 2) {
                const int d0 = 80 + 4 * q;
                float p0 = yc[d0 - 1];
                float4 v4 = *(const float4*)(yc + d0);
                float p5 = (q == 0) ? yc[84] : 0.0f;     // right edge pad at d=87
                float p[6] = {p0, v4.x, v4.y, v4.z, v4.w, p5};
                #pragma unroll
                for (int i = 0; i < 4; i++) {
                    float c0 = fmaf(wc00, p[i], fmaf(wc01, p[i + 1], fmaf(wc02, p[i + 2], bc0)));
                    float c1 = fmaf(wc10, p[i], fmaf(wc11, p[i + 1], fmaf(wc12, p[i + 2], bc1)));
                    af.w[i] = cvtpk(fmaxf(c0, 0.0f), fmaxf(c1, 0.0f));
                }
            } else {
                const int base = (q - 2) * 8;
                #pragma unroll
                for (int j = 0; j < 8; j++)
                    af.h[j] = (short)((base + j == xv) ? 0x3F80 : 0);
            }
            h0 = __builtin_amdgcn_mfma_f32_16x16x32_bf16(af.h, B1[5][0], h0, 0, 0, 0);
            h1 = __builtin_amdgcn_mfma_f32_16x16x32_bf16(af.h, B1[5][1], h1, 0, 0, 0);
            h2 = __builtin_amdgcn_mfma_f32_16x16x32_bf16(af.h, B1[5][2], h2, 0, 0, 0);
        }
        // ---- ks=6: q<2 -> w-onehot dims q*8+j; q==2 -> bias one at j=0; q==3 -> zeros ----
        {
            Frag af;
            if (q < 2) {
                const int base = q * 8;
                #pragma unroll
                for (int j = 0; j < 8; j++)
                    af.h[j] = (short)((base + j == wv) ? 0x3F80 : 0);
            } else {
                #pragma unroll
                for (int j = 0; j < 8; j++)
                    af.h[j] = (short)((q == 2 && j == 0) ? 0x3F80 : 0);
            }
            h0 = __builtin_amdgcn_mfma_f32_16x16x32_bf16(af.h, B1[6][0], h0, 0, 0, 0);
            h1 = __builtin_amdgcn_mfma_f32_16x16x32_bf16(af.h, B1[6][1], h1, 0, 0, 0);
            h2 = __builtin_amdgcn_mfma_f32_16x16x32_bf16(af.h, B1[6][2], h2, 0, 0, 0);
        }

        // ---- epilogue1: relu -> bf16 H in A-frag layout in per-wave LDS ----
        if (lane < 32) {   // chunk 6: bias-one at k2=48 (j==0); chunk 7: zeros
            uint4 hz = make_uint4((lane < 16) ? 0x3F80u : 0u, 0, 0, 0);
            *(uint4*)(sW + ((6 + (lane >> 4)) * 16 + (lane & 15)) * 8) = hz;
        }
        #pragma unroll
        for (int r = 0; r < 4; r++) {
            const int row = q * 4 + r;   // D row = token index in tile
            sW[((0 + (c >> 3)) * 16 + row) * 8 + (c & 7)] = f2bf1(fmaxf(h0[r], 0.0f));
            sW[((2 + (c >> 3)) * 16 + row) * 8 + (c & 7)] = f2bf1(fmaxf(h1[r], 0.0f));
            sW[((4 + (c >> 3)) * 16 + row) * 8 + (c & 7)] = f2bf1(fmaxf(h2[r], 0.0f));
        }

        // ---- GEMM2: out[16x88] = H[16x64] * B2[64x96] ----
        f32x4 o0 = {0,0,0,0}, o1 = {0,0,0,0}, o2 = {0,0,0,0};
        f32x4 o3 = {0,0,0,0}, o4 = {0,0,0,0}, o5 = {0,0,0,0};
        #pragma unroll
        for (int ks = 0; ks < 2; ks++) {
            bf16x8 a2 = *(const bf16x8*)(sW + ((ks * 4 + q) * 16 + c) * 8);
            o0 = __builtin_amdgcn_mfma_f32_16x16x32_bf16(a2, B2[ks][0], o0, 0, 0, 0);
            o1 = __builtin_amdgcn_mfma_f32_16x16x32_bf16(a2, B2[ks][1], o1, 0, 0, 0);
            o2 = __builtin_amdgcn_mfma_f32_16x16x32_bf16(a2, B2[ks][2], o2, 0, 0, 0);
            o3 = __builtin_amdgcn_mfma_f32_16x16x32_bf16(a2, B2[ks][3], o3, 0, 0, 0);
            o4 = __builtin_amdgcn_mfma_f32_16x16x32_bf16(a2, B2[ks][4], o4, 0, 0, 0);
            o5 = __builtin_amdgcn_mfma_f32_16x16x32_bf16(a2, B2[ks][5], o5, 0, 0, 0);
        }

        // ---- store: D row = token (q*4+r), col d = nt*16 + c ----
        float* orow = out + (size_t)(tb + q * 4) * 88;
        #pragma unroll
        for (int r = 0; r < 4; r++) {
            orow[r * 88 +  0 + c] = o0[r];
            orow[r * 88 + 16 + c] = o1[r];
            orow[r * 88 + 32 + c] = o2[r];
            orow[r * 88 + 48 + c] = o3[r];
            orow[r * 88 + 64 + c] = o4[r];
            if (c < 8) orow[r * 88 + 80 + c] = o5[r];
        }
    }
}

extern "C" void kernel_launch(void* const* d_in, const int* in_sizes, int n_in,
                              void* d_out, int out_size, void* d_ws, size_t ws_size,
                              hipStream_t stream) {
    (void)in_sizes; (void)n_in; (void)out_size; (void)d_ws; (void)ws_size;
    tones_v6<<<dim3(NTOK / 256), dim3(TPB), 0, stream>>>(
        (const int*)d_in[0], (const int*)d_in[1], (const float*)d_in[2],
        (const float*)d_in[3], (const float*)d_in[4],
        (const float*)d_in[5], (const float*)d_in[6],
        (const float*)d_in[7], (const float*)d_in[8],
        (const float*)d_in[9], (const float*)d_in[10],
        (const float*)d_in[11], (const float*)d_in[12],
        (float*)d_out);
}

// Round 2
// 136.464 us; speedup vs baseline: 1.0346x; 1.0346x over previous
//
#include <hip/hip_runtime.h>
#include <stdint.h>

// B=256, T=512, f32 tensors. v7: prep kernel pre-swizzles weights into d_ws as
// MFMA-fragment bf16 images (as v5). Main kernel: ONE 16-token tile per wave,
// grid 2048 blocks (4x more waves than v5/v6) to fix the latency-bound 15%
// occupancy seen in rocprof. B-fragments are STREAMED from the L2-resident
// image with a 2-group double buffer (instead of 132 resident VGPRs) so the
// kernel fits 4 waves/SIMD under __launch_bounds__(256,4).
// Conv computed directly in A-fragment layout; only the GEMM1->GEMM2 H
// transpose touches LDS (2 KB/wave). No __syncthreads.
#define NTOK (256 * 512)
#define TPB 256

typedef short bf16x8 __attribute__((ext_vector_type(8)));
typedef float f32x4 __attribute__((ext_vector_type(4)));
typedef unsigned short u16;
typedef unsigned int u32;

#define B1_U16 10752   // 28 chunks * 48 cols * 8
#define B2_U16 6144    // 8 chunks * 96 cols * 8

__device__ __forceinline__ u16 f2bf(float f) {
    u32 u = __float_as_uint(f);
    return (u16)((u + 0x7fffu + ((u >> 16) & 1u)) >> 16);  // rne
}
__device__ __forceinline__ u32 cvtpk(float lo, float hi) {
    u32 r;
    asm("v_cvt_pk_bf16_f32 %0, %1, %2" : "=v"(r) : "v"(lo), "v"(hi));
    return r;
}

// ---------------- prep: build fragment-ordered bf16 weight images ----------------
__global__ __launch_bounds__(256, 1)
void prep_weights(const float* __restrict__ Wxh, const float* __restrict__ bxh,
                  const float* __restrict__ Wwh, const float* __restrict__ bwh,
                  const float* __restrict__ Wyh, const float* __restrict__ byh,
                  const float* __restrict__ Whl, const float* __restrict__ bhl,
                  u16* __restrict__ ws)
{
    int e = blockIdx.x * 256 + threadIdx.x;
    if (e < B1_U16) {
        int j = e & 7, n = (e >> 3) % 48, kc = e / 384;
        int k = kc * 8 + j;                  // k = 2*d + ch for k<176
        float v;
        if (k < 176)       v = Wyh[n * 176 + (k & 1) * 88 + (k >> 1)];
        else if (k < 192)  v = Wxh[n * 16 + (k - 176)];   // x-onehot rows
        else if (k < 208)  v = Wwh[n * 16 + (k - 192)];   // w-onehot rows
        else if (k == 208) v = bxh[n] + bwh[n] + byh[n];  // bias row
        else               v = 0.0f;
        ws[e] = f2bf(v);
    } else if (e < B1_U16 + B2_U16) {
        int e2 = e - B1_U16;
        int j = e2 & 7, dd = (e2 >> 3) % 96, kc = e2 / 768;
        int k = kc * 8 + j;
        float v = 0.0f;
        if (dd < 88) {
            if (k < 48)       v = Whl[dd * 48 + k];
            else if (k == 48) v = bhl[dd];
        }
        ws[e] = f2bf(v);
    }
}

// ---------------- main ----------------
__global__ __launch_bounds__(256, 4)
void tones_v7(const int* __restrict__ widx, const int* __restrict__ xidx,
              const float* __restrict__ y,
              const float* __restrict__ Wconv, const float* __restrict__ bconv,
              const u16* __restrict__ wsb,
              float* __restrict__ out)
{
    __shared__ __align__(16) u16 sH[4 * 1024];   // per-wave H in A-frag layout (2 KB each)

    const int tid = threadIdx.x;
    const int wave = tid >> 6, lane = tid & 63;
    const int q = lane >> 4, c = lane & 15;
    u16* sW = sH + wave * 1024;

    const int tb = blockIdx.x * 64 + wave * 16;          // 16 tokens per wave
    const float* yc = y + (size_t)(tb + c) * 88;         // this lane's token row
    const int xv = xidx[tb + c];
    const int wv = widx[tb + c];

    const float wc00 = Wconv[0], wc01 = Wconv[1], wc02 = Wconv[2];
    const float wc10 = Wconv[3], wc11 = Wconv[4], wc12 = Wconv[5];
    const float bc0 = bconv[0], bc1 = bconv[1];

    // ---- constant LDS chunks 6/7 for GEMM2 (bias one at k2=48, zeros) ----
    if (lane < 32) {
        uint4 hz = make_uint4((lane < 16) ? 0x3F80u : 0u, 0, 0, 0);
        *(uint4*)(sW + ((6 + (lane >> 4)) * 16 + (lane & 15)) * 8) = hz;
    }

    f32x4 h0 = {0, 0, 0, 0}, h1 = {0, 0, 0, 0}, h2 = {0, 0, 0, 0};

    // B1 frag (ks,nt) lives at wsb + ((ks*4+q)*48 + nt*16 + c)*8  (u16 units)
    const u16* bp1 = wsb + (q * 48 + c) * 8;
    // B2 frag (ks,nt) lives at wsb + B1_U16 + ((ks*4+q)*96 + nt*16 + c)*8
    const u16* bp2 = wsb + B1_U16 + (q * 96 + c) * 8;

    // ---- GEMM1: stream B1 with a 2-group (3-frag) double buffer ----
    bf16x8 gA[3], gB[3];
    gA[0] = *(const bf16x8*)(bp1 + 0 * 8);
    gA[1] = *(const bf16x8*)(bp1 + 16 * 8);
    gA[2] = *(const bf16x8*)(bp1 + 32 * 8);

    #pragma unroll
    for (int ks = 0; ks < 7; ks++) {
        bf16x8* cur = (ks & 1) ? gB : gA;
        bf16x8* nxt = (ks & 1) ? gA : gB;
        if (ks < 6) {
            nxt[0] = *(const bf16x8*)(bp1 + ((ks + 1) * 192 +  0) * 8);
            nxt[1] = *(const bf16x8*)(bp1 + ((ks + 1) * 192 + 16) * 8);
            nxt[2] = *(const bf16x8*)(bp1 + ((ks + 1) * 192 + 32) * 8);
        }
        bf16x8 af;
        if (ks < 5) {
            // conv directly in A-frag layout (d0 = 16*ks + 4q)
            const int d0 = 16 * ks + 4 * q;
            float p0 = (d0 == 0) ? 0.0f : yc[d0 - 1];
            float4 v4 = *(const float4*)(yc + d0);
            float p5 = yc[d0 + 4];                       // d0+4 <= 80 < 88
            float p[6] = {p0, v4.x, v4.y, v4.z, v4.w, p5};
            #pragma unroll
            for (int i = 0; i < 4; i++) {
                float c0 = fmaf(wc00, p[i], fmaf(wc01, p[i + 1], fmaf(wc02, p[i + 2], bc0)));
                float c1 = fmaf(wc10, p[i], fmaf(wc11, p[i + 1], fmaf(wc12, p[i + 2], bc1)));
                u32 pk = cvtpk(fmaxf(c0, 0.0f), fmaxf(c1, 0.0f));
                af[2 * i]     = (short)(pk & 0xFFFF);
                af[2 * i + 1] = (short)(pk >> 16);
            }
        } else if (ks == 5) {
            // q<2 -> conv tail (d 80..87); q>=2 -> x-onehot dims (q-2)*8+j
            if (q < 2) {
                const int d0 = 80 + 4 * q;
                float p0 = yc[d0 - 1];
                float4 v4 = *(const float4*)(yc + d0);
                float p5 = (q == 0) ? yc[84] : 0.0f;     // right edge pad at d=87
                float p[6] = {p0, v4.x, v4.y, v4.z, v4.w, p5};
                #pragma unroll
                for (int i = 0; i < 4; i++) {
                    float c0 = fmaf(wc00, p[i], fmaf(wc01, p[i + 1], fmaf(wc02, p[i + 2], bc0)));
                    float c1 = fmaf(wc10, p[i], fmaf(wc11, p[i + 1], fmaf(wc12, p[i + 2], bc1)));
                    u32 pk = cvtpk(fmaxf(c0, 0.0f), fmaxf(c1, 0.0f));
                    af[2 * i]     = (short)(pk & 0xFFFF);
                    af[2 * i + 1] = (short)(pk >> 16);
                }
            } else {
                const int base = (q - 2) * 8;
                #pragma unroll
                for (int j = 0; j < 8; j++)
                    af[j] = (short)((base + j == xv) ? 0x3F80 : 0);
            }
        } else {
            // ks=6: q<2 -> w-onehot dims q*8+j; q==2 -> bias one at j=0; q==3 -> zeros
            if (q < 2) {
                const int base = q * 8;
                #pragma unroll
                for (int j = 0; j < 8; j++)
                    af[j] = (short)((base + j == wv) ? 0x3F80 : 0);
            } else {
                #pragma unroll
                for (int j = 0; j < 8; j++)
                    af[j] = (short)((q == 2 && j == 0) ? 0x3F80 : 0);
            }
        }
        h0 = __builtin_amdgcn_mfma_f32_16x16x32_bf16(af, cur[0], h0, 0, 0, 0);
        h1 = __builtin_amdgcn_mfma_f32_16x16x32_bf16(af, cur[1], h1, 0, 0, 0);
        h2 = __builtin_amdgcn_mfma_f32_16x16x32_bf16(af, cur[2], h2, 0, 0, 0);
    }

    // ---- issue B2 group 0 loads early (overlap with epilogue LDS writes) ----
    bf16x8 b2a[6], b2b[6];
    #pragma unroll
    for (int nt = 0; nt < 6; nt++)
        b2a[nt] = *(const bf16x8*)(bp2 + (nt * 16) * 8);

    // ---- epilogue1: relu -> bf16 H in A-frag layout in per-wave LDS ----
    #pragma unroll
    for (int r = 0; r < 4; r++) {
        const int row = q * 4 + r;   // D row = token index in tile
        sW[((0 + (c >> 3)) * 16 + row) * 8 + (c & 7)] = (u16)cvtpk(fmaxf(h0[r], 0.0f), 0.0f);
        sW[((2 + (c >> 3)) * 16 + row) * 8 + (c & 7)] = (u16)cvtpk(fmaxf(h1[r], 0.0f), 0.0f);
        sW[((4 + (c >> 3)) * 16 + row) * 8 + (c & 7)] = (u16)cvtpk(fmaxf(h2[r], 0.0f), 0.0f);
    }

    #pragma unroll
    for (int nt = 0; nt < 6; nt++)
        b2b[nt] = *(const bf16x8*)(bp2 + (384 + nt * 16) * 8);

    // ---- GEMM2: out[16x88] = H[16x64] * B2[64x96] ----
    f32x4 o0 = {0,0,0,0}, o1 = {0,0,0,0}, o2 = {0,0,0,0};
    f32x4 o3 = {0,0,0,0}, o4 = {0,0,0,0}, o5 = {0,0,0,0};
    {
        bf16x8 a2 = *(const bf16x8*)(sW + (q * 16 + c) * 8);
        o0 = __builtin_amdgcn_mfma_f32_16x16x32_bf16(a2, b2a[0], o0, 0, 0, 0);
        o1 = __builtin_amdgcn_mfma_f32_16x16x32_bf16(a2, b2a[1], o1, 0, 0, 0);
        o2 = __builtin_amdgcn_mfma_f32_16x16x32_bf16(a2, b2a[2], o2, 0, 0, 0);
        o3 = __builtin_amdgcn_mfma_f32_16x16x32_bf16(a2, b2a[3], o3, 0, 0, 0);
        o4 = __builtin_amdgcn_mfma_f32_16x16x32_bf16(a2, b2a[4], o4, 0, 0, 0);
        o5 = __builtin_amdgcn_mfma_f32_16x16x32_bf16(a2, b2a[5], o5, 0, 0, 0);
    }
    {
        bf16x8 a2 = *(const bf16x8*)(sW + ((4 + q) * 16 + c) * 8);
        o0 = __builtin_amdgcn_mfma_f32_16x16x32_bf16(a2, b2b[0], o0, 0, 0, 0);
        o1 = __builtin_amdgcn_mfma_f32_16x16x32_bf16(a2, b2b[1], o1, 0, 0, 0);
        o2 = __builtin_amdgcn_mfma_f32_16x16x32_bf16(a2, b2b[2], o2, 0, 0, 0);
        o3 = __builtin_amdgcn_mfma_f32_16x16x32_bf16(a2, b2b[3], o3, 0, 0, 0);
        o4 = __builtin_amdgcn_mfma_f32_16x16x32_bf16(a2, b2b[4], o4, 0, 0, 0);
        o5 = __builtin_amdgcn_mfma_f32_16x16x32_bf16(a2, b2b[5], o5, 0, 0, 0);
    }

    // ---- store: D row = token (q*4+r), col d = nt*16 + c ----
    float* orow = out + (size_t)(tb + q * 4) * 88;
    #pragma unroll
    for (int r = 0; r < 4; r++) {
        orow[r * 88 +  0 + c] = o0[r];
        orow[r * 88 + 16 + c] = o1[r];
        orow[r * 88 + 32 + c] = o2[r];
        orow[r * 88 + 48 + c] = o3[r];
        orow[r * 88 + 64 + c] = o4[r];
        if (c < 8) orow[r * 88 + 80 + c] = o5[r];
    }
}

extern "C" void kernel_launch(void* const* d_in, const int* in_sizes, int n_in,
                              void* d_out, int out_size, void* d_ws, size_t ws_size,
                              hipStream_t stream) {
    (void)in_sizes; (void)n_in; (void)out_size; (void)ws_size;
    u16* ws = (u16*)d_ws;
    prep_weights<<<dim3(66), dim3(TPB), 0, stream>>>(
        (const float*)d_in[3],  (const float*)d_in[4],
        (const float*)d_in[5],  (const float*)d_in[6],
        (const float*)d_in[7],  (const float*)d_in[8],
        (const float*)d_in[11], (const float*)d_in[12], ws);
    tones_v7<<<dim3(NTOK / 64), dim3(TPB), 0, stream>>>(
        (const int*)d_in[0], (const int*)d_in[1], (const float*)d_in[2],
        (const float*)d_in[9], (const float*)d_in[10], ws, (float*)d_out);
}

// Round 3
// 124.719 us; speedup vs baseline: 1.1320x; 1.0942x over previous
//
#include <hip/hip_runtime.h>
#include <stdint.h>

// B=256, T=512, f32. v8: prep kernel builds fragment-ordered bf16 weight image
// in d_ws (as v5/v7). Main kernel: block stages the 33.8 KB weight image into
// LDS once (global_load_lds, 1 barrier) and each wave stages its contiguous
// 5.6 KB y-tile into LDS; all fragment/conv reads become LDS reads. This cuts
// per-wave VMEM instructions ~76 -> ~31 and removes the scattered-line TA load
// that capped v5-v7 at ~41 us. 16 tokens/wave, 2048 blocks, 2 blocks/CU.
#define NTOK (256 * 512)
#define TPB 256

typedef short bf16x8 __attribute__((ext_vector_type(8)));
typedef float f32x4 __attribute__((ext_vector_type(4)));
typedef unsigned short u16;
typedef unsigned int u32;

#define B1_U16 10752   // 28 chunks * 48 cols * 8 u16
#define B2_U16 6144    // 8 chunks * 96 cols * 8 u16
#define W_BYTES ((B1_U16 + B2_U16) * 2)       // 33792
#define W_CHUNKS (W_BYTES / 16)               // 2112 16B chunks
#define YB_U16 2816                           // 5632 B per-wave y tile
#define H_U16 1024                            // 2 KB per-wave H buffer

__device__ __forceinline__ u16 f2bf(float f) {
    u32 u = __float_as_uint(f);
    return (u16)((u + 0x7fffu + ((u >> 16) & 1u)) >> 16);  // rne
}
__device__ __forceinline__ u32 cvtpk(float lo, float hi) {
    u32 r;
    asm("v_cvt_pk_bf16_f32 %0, %1, %2" : "=v"(r) : "v"(lo), "v"(hi));
    return r;
}
__device__ __forceinline__ void gll16(const void* g, void* l) {
    __builtin_amdgcn_global_load_lds(
        (const __attribute__((address_space(1))) void*)g,
        (__attribute__((address_space(3))) void*)l, 16, 0, 0);
}
__device__ __forceinline__ void gll4(const void* g, void* l) {
    __builtin_amdgcn_global_load_lds(
        (const __attribute__((address_space(1))) void*)g,
        (__attribute__((address_space(3))) void*)l, 4, 0, 0);
}

// ---------------- prep: build fragment-ordered bf16 weight image ----------------
__global__ __launch_bounds__(256, 1)
void prep_weights(const float* __restrict__ Wxh, const float* __restrict__ bxh,
                  const float* __restrict__ Wwh, const float* __restrict__ bwh,
                  const float* __restrict__ Wyh, const float* __restrict__ byh,
                  const float* __restrict__ Whl, const float* __restrict__ bhl,
                  u16* __restrict__ ws)
{
    int e = blockIdx.x * 256 + threadIdx.x;
    if (e < B1_U16) {
        int j = e & 7, n = (e >> 3) % 48, kc = e / 384;
        int k = kc * 8 + j;                  // k = 2*d + ch for k<176
        float v;
        if (k < 176)       v = Wyh[n * 176 + (k & 1) * 88 + (k >> 1)];
        else if (k < 192)  v = Wxh[n * 16 + (k - 176)];   // x-onehot rows
        else if (k < 208)  v = Wwh[n * 16 + (k - 192)];   // w-onehot rows
        else if (k == 208) v = bxh[n] + bwh[n] + byh[n];  // bias row
        else               v = 0.0f;
        ws[e] = f2bf(v);
    } else if (e < B1_U16 + B2_U16) {
        int e2 = e - B1_U16;
        int j = e2 & 7, dd = (e2 >> 3) % 96, kc = e2 / 768;
        int k = kc * 8 + j;
        float v = 0.0f;
        if (dd < 88) {
            if (k < 48)       v = Whl[dd * 48 + k];
            else if (k == 48) v = bhl[dd];
        }
        ws[e] = f2bf(v);
    }
}

// ---------------- main ----------------
__global__ __launch_bounds__(256, 2)
void tones_v8(const int* __restrict__ widx, const int* __restrict__ xidx,
              const float* __restrict__ y,
              const float* __restrict__ Wconv, const float* __restrict__ bconv,
              const u16* __restrict__ wsb,
              float* __restrict__ out)
{
    // [0, 16896)                weights, verbatim d_ws image (u16 units)
    // [16896 + wave*2816 ...)   per-wave y tile (1408 f32)
    // [28160 + wave*1024 ...)   per-wave H fragment buffer
    __shared__ __align__(16) u16 lds[32256];

    const int tid = threadIdx.x;
    const int wave = tid >> 6, lane = tid & 63;
    const int q = lane >> 4, c = lane & 15;

    const int tb = blockIdx.x * 64 + wave * 16;          // 16 tokens per wave

    // ---- stage weight image into LDS (cooperative across 4 waves) ----
    #pragma unroll
    for (int i = 0; i < 8; i++) {
        const int cb = i * 256 + wave * 64;              // chunk base for this wave
        gll16((const char*)wsb + (cb + lane) * 16, (char*)lds + cb * 16);
    }
    if (wave == 0) {                                     // chunks 2048..2111
        const int cb = 2048;
        gll16((const char*)wsb + (cb + lane) * 16, (char*)lds + cb * 16);
    }

    // ---- stage this wave's y tile (contiguous 5632 B) into LDS ----
    u16* sYu = lds + 16896 + wave * YB_U16;
    {
        const char* yt = (const char*)(y + (size_t)tb * 88);
        char* dst = (char*)sYu;
        #pragma unroll
        for (int j = 0; j < 5; j++)
            gll16(yt + j * 1024 + lane * 16, dst + j * 1024);
        #pragma unroll
        for (int k = 0; k < 2; k++)
            gll4(yt + 5120 + k * 256 + lane * 4, dst + 5120 + k * 256);
    }

    const int xv = xidx[tb + c];
    const int wv = widx[tb + c];
    const float wc00 = Wconv[0], wc01 = Wconv[1], wc02 = Wconv[2];
    const float wc10 = Wconv[3], wc11 = Wconv[4], wc12 = Wconv[5];
    const float bc0 = bconv[0], bc1 = bconv[1];

    // ---- constant H chunks 6/7 for GEMM2 (bias one at k2=48, zeros) ----
    u16* sW = lds + 28160 + wave * H_U16;
    if (lane < 32) {
        uint4 hz = make_uint4((lane < 16) ? 0x3F80u : 0u, 0, 0, 0);
        *(uint4*)(sW + ((6 + (lane >> 4)) * 16 + (lane & 15)) * 8) = hz;
    }

    __syncthreads();   // drains global_load_lds (vmcnt) + makes weights visible

    const float* yr = (const float*)sYu + c * 88;        // this lane's token row

    f32x4 h0 = {0, 0, 0, 0}, h1 = {0, 0, 0, 0}, h2 = {0, 0, 0, 0};

    // B1 frag (ks,nt) at u16 index ((ks*4+q)*48 + nt*16 + c)*8
    const u16* f1 = lds + (q * 48 + c) * 8;
    // B2 frag (ks,nt) at u16 index B1_U16 + ((ks*4+q)*96 + nt*16 + c)*8
    const u16* f2 = lds + B1_U16 + (q * 96 + c) * 8;

    #pragma unroll
    for (int ks = 0; ks < 7; ks++) {
        bf16x8 af;
        if (ks < 5) {
            // conv directly in A-frag layout (d0 = 16*ks + 4q)
            const int d0 = 16 * ks + 4 * q;
            float p0 = (d0 == 0) ? 0.0f : yr[d0 - 1];
            f32x4 v4 = *(const f32x4*)(yr + d0);
            float p5 = yr[d0 + 4];                       // d0+4 <= 80 < 88
            float p[6] = {p0, v4[0], v4[1], v4[2], v4[3], p5};
            #pragma unroll
            for (int i = 0; i < 4; i++) {
                float c0 = fmaf(wc00, p[i], fmaf(wc01, p[i + 1], fmaf(wc02, p[i + 2], bc0)));
                float c1 = fmaf(wc10, p[i], fmaf(wc11, p[i + 1], fmaf(wc12, p[i + 2], bc1)));
                u32 pk = cvtpk(fmaxf(c0, 0.0f), fmaxf(c1, 0.0f));
                af[2 * i]     = (short)(pk & 0xFFFF);
                af[2 * i + 1] = (short)(pk >> 16);
            }
        } else if (ks == 5) {
            // q<2 -> conv tail (d 80..87); q>=2 -> x-onehot dims (q-2)*8+j
            if (q < 2) {
                const int d0 = 80 + 4 * q;
                float p0 = yr[d0 - 1];
                f32x4 v4 = *(const f32x4*)(yr + d0);
                float p5 = (q == 0) ? yr[84] : 0.0f;     // right edge pad at d=87
                float p[6] = {p0, v4[0], v4[1], v4[2], v4[3], p5};
                #pragma unroll
                for (int i = 0; i < 4; i++) {
                    float c0 = fmaf(wc00, p[i], fmaf(wc01, p[i + 1], fmaf(wc02, p[i + 2], bc0)));
                    float c1 = fmaf(wc10, p[i], fmaf(wc11, p[i + 1], fmaf(wc12, p[i + 2], bc1)));
                    u32 pk = cvtpk(fmaxf(c0, 0.0f), fmaxf(c1, 0.0f));
                    af[2 * i]     = (short)(pk & 0xFFFF);
                    af[2 * i + 1] = (short)(pk >> 16);
                }
            } else {
                const int base = (q - 2) * 8;
                #pragma unroll
                for (int j = 0; j < 8; j++)
                    af[j] = (short)((base + j == xv) ? 0x3F80 : 0);
            }
        } else {
            // ks=6: q<2 -> w-onehot dims q*8+j; q==2 -> bias one at j=0; q==3 -> zeros
            if (q < 2) {
                const int base = q * 8;
                #pragma unroll
                for (int j = 0; j < 8; j++)
                    af[j] = (short)((base + j == wv) ? 0x3F80 : 0);
            } else {
                #pragma unroll
                for (int j = 0; j < 8; j++)
                    af[j] = (short)((q == 2 && j == 0) ? 0x3F80 : 0);
            }
        }
        bf16x8 b0 = *(const bf16x8*)(f1 + (ks * 192 +  0) * 8);
        bf16x8 b1 = *(const bf16x8*)(f1 + (ks * 192 + 16) * 8);
        bf16x8 b2 = *(const bf16x8*)(f1 + (ks * 192 + 32) * 8);
        h0 = __builtin_amdgcn_mfma_f32_16x16x32_bf16(af, b0, h0, 0, 0, 0);
        h1 = __builtin_amdgcn_mfma_f32_16x16x32_bf16(af, b1, h1, 0, 0, 0);
        h2 = __builtin_amdgcn_mfma_f32_16x16x32_bf16(af, b2, h2, 0, 0, 0);
    }

    // ---- epilogue1: relu -> bf16 H in A-frag layout in per-wave LDS ----
    #pragma unroll
    for (int r = 0; r < 4; r++) {
        const int row = q * 4 + r;   // D row = token index in tile
        sW[((0 + (c >> 3)) * 16 + row) * 8 + (c & 7)] = (u16)cvtpk(fmaxf(h0[r], 0.0f), 0.0f);
        sW[((2 + (c >> 3)) * 16 + row) * 8 + (c & 7)] = (u16)cvtpk(fmaxf(h1[r], 0.0f), 0.0f);
        sW[((4 + (c >> 3)) * 16 + row) * 8 + (c & 7)] = (u16)cvtpk(fmaxf(h2[r], 0.0f), 0.0f);
    }

    // ---- GEMM2: out[16x88] = H[16x64] * B2[64x96] ----
    f32x4 o0 = {0,0,0,0}, o1 = {0,0,0,0}, o2 = {0,0,0,0};
    f32x4 o3 = {0,0,0,0}, o4 = {0,0,0,0}, o5 = {0,0,0,0};
    #pragma unroll
    for (int ks = 0; ks < 2; ks++) {
        bf16x8 a2 = *(const bf16x8*)(sW + ((ks * 4 + q) * 16 + c) * 8);
        bf16x8 w0 = *(const bf16x8*)(f2 + (ks * 384 +  0) * 8);
        bf16x8 w1 = *(const bf16x8*)(f2 + (ks * 384 + 16) * 8);
        bf16x8 w2 = *(const bf16x8*)(f2 + (ks * 384 + 32) * 8);
        bf16x8 w3 = *(const bf16x8*)(f2 + (ks * 384 + 48) * 8);
        bf16x8 w4 = *(const bf16x8*)(f2 + (ks * 384 + 64) * 8);
        bf16x8 w5 = *(const bf16x8*)(f2 + (ks * 384 + 80) * 8);
        o0 = __builtin_amdgcn_mfma_f32_16x16x32_bf16(a2, w0, o0, 0, 0, 0);
        o1 = __builtin_amdgcn_mfma_f32_16x16x32_bf16(a2, w1, o1, 0, 0, 0);
        o2 = __builtin_amdgcn_mfma_f32_16x16x32_bf16(a2, w2, o2, 0, 0, 0);
        o3 = __builtin_amdgcn_mfma_f32_16x16x32_bf16(a2, w3, o3, 0, 0, 0);
        o4 = __builtin_amdgcn_mfma_f32_16x16x32_bf16(a2, w4, o4, 0, 0, 0);
        o5 = __builtin_amdgcn_mfma_f32_16x16x32_bf16(a2, w5, o5, 0, 0, 0);
    }

    // ---- store: D row = token (q*4+r), col d = nt*16 + c ----
    float* orow = out + (size_t)(tb + q * 4) * 88;
    #pragma unroll
    for (int r = 0; r < 4; r++) {
        orow[r * 88 +  0 + c] = o0[r];
        orow[r * 88 + 16 + c] = o1[r];
        orow[r * 88 + 32 + c] = o2[r];
        orow[r * 88 + 48 + c] = o3[r];
        orow[r * 88 + 64 + c] = o4[r];
        if (c < 8) orow[r * 88 + 80 + c] = o5[r];
    }
}

extern "C" void kernel_launch(void* const* d_in, const int* in_sizes, int n_in,
                              void* d_out, int out_size, void* d_ws, size_t ws_size,
                              hipStream_t stream) {
    (void)in_sizes; (void)n_in; (void)out_size; (void)ws_size;
    u16* ws = (u16*)d_ws;
    prep_weights<<<dim3(66), dim3(TPB), 0, stream>>>(
        (const float*)d_in[3],  (const float*)d_in[4],
        (const float*)d_in[5],  (const float*)d_in[6],
        (const float*)d_in[7],  (const float*)d_in[8],
        (const float*)d_in[11], (const float*)d_in[12], ws);
    tones_v8<<<dim3(NTOK / 64), dim3(TPB), 0, stream>>>(
        (const int*)d_in[0], (const int*)d_in[1], (const float*)d_in[2],
        (const float*)d_in[9], (const float*)d_in[10], ws, (float*)d_out);
}